// Round 1
// baseline (723.436 us; speedup 1.0000x reference)
//
#include <hip/hip_runtime.h>
#include <hip/hip_bf16.h>

#define HIDDEN 896
#define HEADS 7
#define HDIM 128
#define BB 4
#define TT 2048
#define MTOT (BB*TT)   // 8192

typedef short bf16x8 __attribute__((ext_vector_type(8)));
typedef float f32x4 __attribute__((ext_vector_type(4)));

__device__ __forceinline__ short f2bf(float f) {
    union { float f; unsigned u; } v; v.f = f;
    unsigned r = (v.u + 0x7FFF + ((v.u >> 16) & 1)) >> 16;
    return (short)r;
}

// async global->LDS, 16B per lane; lds dst must be wave-uniform base (+lane*16 implicit)
__device__ __forceinline__ void gll16(const short* g, short* l) {
    __builtin_amdgcn_global_load_lds(
        (const __attribute__((address_space(1))) unsigned int*)g,
        (__attribute__((address_space(3))) unsigned int*)l, 16, 0, 0);
}

// ---------------- kernel 1: cast x (fp32) -> bf16 ----------------
__global__ __launch_bounds__(256) void cast_x_kernel(const float* __restrict__ x,
                                                     short* __restrict__ xb) {
    int base = (blockIdx.x * 256 + threadIdx.x) * 4;
    if (base < MTOT * HIDDEN) {
        float4 v = *(const float4*)(x + base);
        short4 o;
        o.x = f2bf(v.x); o.y = f2bf(v.y); o.z = f2bf(v.z); o.w = f2bf(v.w);
        *(short4*)(xb + base) = o;
    }
}

// cast Wo fp32[896][896] -> bf16 (already B^T form [n][k])
__global__ __launch_bounds__(256) void cast_wo_kernel(const float* __restrict__ src,
                                                      short* __restrict__ dst) {
    int base = (blockIdx.x * 256 + threadIdx.x) * 4;
    if (base < HIDDEN * HIDDEN) {
        float4 v = *(const float4*)(src + base);
        short4 o;
        o.x = f2bf(v.x); o.y = f2bf(v.y); o.z = f2bf(v.z); o.w = f2bf(v.w);
        *(short4*)(dst + base) = o;
    }
}

// transpose-cast Wq/Wk/Wv fp32 [head][896 k][128 n] -> bf16 Wt[type*7+head][128 n][896 k]
__global__ __launch_bounds__(256) void transpose_cast_w(
    const float* __restrict__ Wq, const float* __restrict__ Wk,
    const float* __restrict__ Wv, short* __restrict__ Wt)
{
    __shared__ float tile[32][33];
    const int z = blockIdx.z;
    const int type = z / 7, head = z % 7;
    const float* src = (type == 0 ? Wq : (type == 1 ? Wk : Wv)) + head * (HIDDEN * HDIM);
    short* dst = Wt + (size_t)z * (HDIM * HIDDEN);
    const int r0 = blockIdx.x * 32, c0 = blockIdx.y * 32;
    const int tx = threadIdx.x & 31, ty = threadIdx.x >> 5;  // 32 x 8
    for (int i = 0; i < 4; i++)
        tile[ty * 4 + i][tx] = src[(r0 + ty * 4 + i) * HDIM + c0 + tx];
    __syncthreads();
    for (int i = 0; i < 4; i++)
        dst[(c0 + ty * 4 + i) * HIDDEN + r0 + tx] = f2bf(tile[tx][ty * 4 + i]);
}

// ---------------- kernel 2: QKV projection GEMM (128x128, global_load_lds) ----------------
__global__ __launch_bounds__(256) void qkv_gemm(
    const short* __restrict__ xb, const short* __restrict__ Wt,
    short* __restrict__ Q, short* __restrict__ Kk, short* __restrict__ Vt)
{
    __shared__ short Ash[128 * 32];
    __shared__ short Bsh[128 * 32];
    const int m0 = blockIdx.x * 128;
    const int z = blockIdx.y;
    const int head = z % 7, type = z / 7;
    const short* Wz = Wt + (size_t)z * (HDIM * HIDDEN);

    const int tid = threadIdx.x;
    const int wave = tid >> 6, lane = tid & 63;
    const int quad = lane >> 4, l16 = lane & 15;
    const int wm = (wave >> 1) * 64, wn = (wave & 1) * 64;

    f32x4 acc[4][4] = {};

    const int r0 = tid >> 2, cc0 = (tid & 3) * 8;
    const int r1 = r0 + 64;
    short* adst0 = Ash + wave * 512;
    short* adst1 = Ash + 2048 + wave * 512;
    short* bdst0 = Bsh + wave * 512;
    short* bdst1 = Bsh + 2048 + wave * 512;
    const short* asrc0 = xb + (size_t)(m0 + r0) * HIDDEN + cc0;
    const short* asrc1 = xb + (size_t)(m0 + r1) * HIDDEN + cc0;
    const short* bsrc0 = Wz + (size_t)r0 * HIDDEN + cc0;
    const short* bsrc1 = Wz + (size_t)r1 * HIDDEN + cc0;

    for (int k0 = 0; k0 < HIDDEN; k0 += 32) {
        __syncthreads();                 // prev tile fully consumed
        gll16(asrc0 + k0, adst0);
        gll16(asrc1 + k0, adst1);
        gll16(bsrc0 + k0, bdst0);
        gll16(bsrc1 + k0, bdst1);
        __syncthreads();                 // drains vmcnt -> LDS tile ready
        bf16x8 af[4], bfr[4];
        for (int mi = 0; mi < 4; mi++)
            af[mi] = *(const bf16x8*)(Ash + (wm + mi * 16 + l16) * 32 + quad * 8);
        for (int ni = 0; ni < 4; ni++)
            bfr[ni] = *(const bf16x8*)(Bsh + (wn + ni * 16 + l16) * 32 + quad * 8);
        for (int mi = 0; mi < 4; mi++)
            for (int ni = 0; ni < 4; ni++)
                acc[mi][ni] = __builtin_amdgcn_mfma_f32_16x16x32_bf16(af[mi], bfr[ni], acc[mi][ni], 0, 0, 0);
    }

    const size_t base = (size_t)head * (MTOT * HDIM);
    if (type == 0) {
        // fold softmax scale AND log2(e) into Q (softmax done in exp2 domain)
        const float qs = 0.08838834764831845f * 1.4426950408889634f;
        for (int mi = 0; mi < 4; mi++)
            for (int ni = 0; ni < 4; ni++)
                for (int r = 0; r < 4; r++) {
                    int m = m0 + wm + mi * 16 + quad * 4 + r;
                    int n = wn + ni * 16 + l16;
                    Q[base + (size_t)m * HDIM + n] = f2bf(acc[mi][ni][r] * qs);
                }
    } else if (type == 1) {
        for (int mi = 0; mi < 4; mi++)
            for (int ni = 0; ni < 4; ni++)
                for (int r = 0; r < 4; r++) {
                    int m = m0 + wm + mi * 16 + quad * 4 + r;
                    int n = wn + ni * 16 + l16;
                    Kk[base + (size_t)m * HDIM + n] = f2bf(acc[mi][ni][r]);
                }
    } else {
        for (int mi = 0; mi < 4; mi++)
            for (int ni = 0; ni < 4; ni++) {
                int m = m0 + wm + mi * 16 + quad * 4;
                int bb = m >> 11, t = m & 2047;
                int n = wn + ni * 16 + l16;
                short4 o;
                o.x = f2bf(acc[mi][ni][0]); o.y = f2bf(acc[mi][ni][1]);
                o.z = f2bf(acc[mi][ni][2]); o.w = f2bf(acc[mi][ni][3]);
                *(short4*)(Vt + base + (size_t)bb * (HDIM * TT) + (size_t)n * TT + t) = o;
            }
    }
}

// ---------------- kernel 2.5: zero split accumulators ----------------
// Of32 = 7*4*1024*128 floats (aliases xb, free after qkv_gemm); lf32 = 7*4*1024 floats
#define OF32_N (HEADS * BB * 1024 * HDIM)   // 3670016
#define LF32_N (HEADS * BB * 1024)          // 28672
__global__ __launch_bounds__(256) void zero_acc(float* __restrict__ Of32,
                                                float* __restrict__ lf32) {
    int idx = blockIdx.x * 256 + threadIdx.x;
    if (idx < OF32_N / 4)
        *(float4*)(Of32 + idx * 4) = make_float4(0.f, 0.f, 0.f, 0.f);
    if (idx < LF32_N / 4)
        *(float4*)(lf32 + idx * 4) = make_float4(0.f, 0.f, 0.f, 0.f);
}

// ---------------- kernel 3: fano flash attention v9 (split-S for long q-tiles) ----------------
// Grid: (16 qt, 8 s-chunks, 28 b*h). qt<8: chunk 0 does the whole (short) s-range and
// writes Ocat directly (full softmax sum local). qt>=8: each chunk does <=4 s-steps and
// atomicAdds unnormalized partial (oacc,lacc) into f32 accumulators — valid because this
// kernel uses no online max (scores -> exp2 directly), so partials are linearly additive.
__global__ __launch_bounds__(256, 3) void fano_attn(
    const short* __restrict__ Q, const short* __restrict__ K, const short* __restrict__ Vt,
    short* __restrict__ Ocat, float* __restrict__ Of32, float* __restrict__ lf32,
    const int* __restrict__ iscp)
{
    __shared__ short Ks[64 * 136];
    __shared__ short Vs[128 * 72];
    __shared__ short Ps[4][32 * 72];

    const int causal = *iscp;
    const int qt = blockIdx.x;
    const int ck = blockIdx.y;
    const int b = blockIdx.z & 3, h = blockIdx.z >> 2;
    const int q0 = qt * 128;

    const int nsteps = causal ? (qt * 2 + 2) : (TT / 64);
    const bool split = (qt >= 8);
    int step_lo, step_hi;
    if (split) {
        step_lo = ck * 4;
        if (step_lo >= nsteps) return;
        step_hi = step_lo + 4; if (step_hi > nsteps) step_hi = nsteps;
    } else {
        if (ck != 0) return;
        step_lo = 0; step_hi = nsteps;
    }
    const int s_init = step_lo * 64;
    const int send = step_hi * 64;      // exclusive col bound for this block

    const int tid = threadIdx.x, wave = tid >> 6, lane = tid & 63;
    const int quad = lane >> 4, l16 = lane & 15;
    const int iw = q0 + wave * 32;   // wave's min q-row

    const short* Qb = Q + (size_t)(h * MTOT + b * TT + q0) * HDIM;
    const short* Kb = K + (size_t)(h * MTOT + b * TT) * HDIM;
    const short* Vb = Vt + (size_t)h * MTOT * HDIM + (size_t)b * HDIM * TT;

    bf16x8 qf[2][4];
    for (int g = 0; g < 2; g++)
        for (int ks = 0; ks < 4; ks++)
            qf[g][ks] = *(const bf16x8*)(Qb + (size_t)(wave * 32 + g * 16 + l16) * HDIM + ks * 32 + quad * 8);

    f32x4 oacc[2][8] = {};
    f32x4 lacc[2] = {};
    int irow[2][4];
    for (int g = 0; g < 2; g++)
        for (int r = 0; r < 4; r++)
            irow[g][r] = q0 + wave * 32 + g * 16 + quad * 4 + r;

    const bf16x8 vones = {0x3F80, 0x3F80, 0x3F80, 0x3F80, 0x3F80, 0x3F80, 0x3F80, 0x3F80};

    int krow[4], kcol[4], vrow[4], vcol[4];
    for (int i = 0; i < 4; i++) {
        int c = tid + i * 256;
        krow[i] = c >> 4; kcol[i] = (c & 15) * 8;
        vrow[i] = c >> 3; vcol[i] = (c & 7) * 8;
    }

    bf16x8 kreg[4], vreg[4];
    for (int i = 0; i < 4; i++) {
        kreg[i] = *(const bf16x8*)(Kb + (size_t)(s_init + krow[i]) * HDIM + kcol[i]);
        vreg[i] = *(const bf16x8*)(Vb + (size_t)vrow[i] * TT + s_init + vcol[i]);
    }

    int d7b = (l16 - h + 7 + step_lo) % 7;
    short* Pw = &Ps[wave][0];

    for (int s0 = s_init; s0 < send; s0 += 64) {
        __syncthreads();
        for (int i = 0; i < 4; i++) {
            *(bf16x8*)(Ks + krow[i] * 136 + kcol[i]) = kreg[i];
            *(bf16x8*)(Vs + vrow[i] * 72 + vcol[i]) = vreg[i];
        }
        __syncthreads();

        int sn = s0 + 64; if (sn >= send) sn = s0;
        const short* Kn = Kb + (size_t)sn * HDIM;
        const short* Vn = Vb + sn;
        for (int i = 0; i < 4; i++) {
            kreg[i] = *(const bf16x8*)(Kn + (size_t)krow[i] * HDIM + kcol[i]);
            vreg[i] = *(const bf16x8*)(Vn + (size_t)vrow[i] * TT + vcol[i]);
        }

        f32x4 sacc[2][4] = {};
        for (int ni = 0; ni < 4; ni++)
            for (int ks = 0; ks < 4; ks++) {
                bf16x8 bk = *(const bf16x8*)(Ks + (ni * 16 + l16) * 136 + ks * 32 + quad * 8);
                sacc[0][ni] = __builtin_amdgcn_mfma_f32_16x16x32_bf16(qf[0][ks], bk, sacc[0][ni], 0, 0, 0);
                sacc[1][ni] = __builtin_amdgcn_mfma_f32_16x16x32_bf16(qf[1][ks], bk, sacc[1][ni], 0, 0, 0);
            }

        const bool full = (s0 + 80 > iw) && (causal || (s0 < iw + 48));
        if (full) {
            for (int ni = 0; ni < 4; ni++) {
                int d7 = d7b + 2 * ni; if (d7 >= 7) d7 -= 7;
                bool line = (0x0B >> d7) & 1;
                int s = s0 + ni * 16 + l16;
                for (int g = 0; g < 2; g++)
                    for (int r = 0; r < 4; r++) {
                        int i = irow[g][r];
                        bool ok = causal ? ((s <= i) & (line | (s >= i - 16)))
                                         : (line | ((s >= i - 16) & (s <= i + 16)));
                        sacc[g][ni][r] = ok ? exp2f(sacc[g][ni][r]) : 0.0f;
                    }
            }
        } else {
            for (int ni = 0; ni < 4; ni++) {
                int d7 = d7b + 2 * ni; if (d7 >= 7) d7 -= 7;
                bool line = (0x0B >> d7) & 1;
                for (int g = 0; g < 2; g++)
                    for (int r = 0; r < 4; r++)
                        sacc[g][ni][r] = line ? exp2f(sacc[g][ni][r]) : 0.0f;
            }
        }
        d7b++; if (d7b == 7) d7b = 0;

        for (int g = 0; g < 2; g++)
            for (int ni = 0; ni < 4; ni++)
                for (int r = 0; r < 4; r++)
                    Pw[(g * 16 + quad * 4 + r) * 72 + ni * 16 + l16] = f2bf(sacc[g][ni][r]);

        for (int ks2 = 0; ks2 < 2; ks2++) {
            bf16x8 ap0 = *(const bf16x8*)(Pw + l16 * 72 + ks2 * 32 + quad * 8);
            bf16x8 ap1 = *(const bf16x8*)(Pw + (16 + l16) * 72 + ks2 * 32 + quad * 8);
            lacc[0] = __builtin_amdgcn_mfma_f32_16x16x32_bf16(ap0, vones, lacc[0], 0, 0, 0);
            lacc[1] = __builtin_amdgcn_mfma_f32_16x16x32_bf16(ap1, vones, lacc[1], 0, 0, 0);
            for (int nj = 0; nj < 8; nj++) {
                bf16x8 bv = *(const bf16x8*)(Vs + (nj * 16 + l16) * 72 + ks2 * 32 + quad * 8);
                oacc[0][nj] = __builtin_amdgcn_mfma_f32_16x16x32_bf16(ap0, bv, oacc[0][nj], 0, 0, 0);
                oacc[1][nj] = __builtin_amdgcn_mfma_f32_16x16x32_bf16(ap1, bv, oacc[1][nj], 0, 0, 0);
            }
        }
    }

    if (!split) {
        // full s-range done locally -> normalize and write bf16 Ocat directly
        short* Obase = Ocat + (size_t)(b * TT) * HIDDEN + h * HDIM;
        for (int g = 0; g < 2; g++) {
            float inv[4];
            for (int r = 0; r < 4; r++) inv[r] = 1.0f / lacc[g][r];
            for (int nj = 0; nj < 8; nj++)
                for (int r = 0; r < 4; r++)
                    Obase[(size_t)irow[g][r] * HIDDEN + nj * 16 + l16] = f2bf(oacc[g][nj][r] * inv[r]);
        }
    } else {
        // partial tile -> accumulate into f32 buffers (rows 1024..2047 per (b,h))
        float* Ob = Of32 + (size_t)(h * 4 + b) * 1024 * HDIM;
        float* lb = lf32 + (h * 4 + b) * 1024;
        for (int g = 0; g < 2; g++) {
            for (int nj = 0; nj < 8; nj++)
                for (int r = 0; r < 4; r++)
                    atomicAdd(&Ob[(size_t)(irow[g][r] - 1024) * HDIM + nj * 16 + l16],
                              oacc[g][nj][r]);
            if (l16 == 0)
                for (int r = 0; r < 4; r++)
                    atomicAdd(&lb[irow[g][r] - 1024], lacc[g][r]);
        }
    }
}

// ---------------- kernel 3.5: normalize split rows -> Ocat bf16 ----------------
__global__ __launch_bounds__(256) void attn_norm(const float* __restrict__ Of32,
                                                 const float* __restrict__ lf32,
                                                 short* __restrict__ Ocat) {
    int idx = blockIdx.x * 256 + threadIdx.x;        // one float4 per thread
    if (idx >= OF32_N / 4) return;
    int e = idx * 4;
    int hb = e >> 17;                 // / (1024*128)
    int rem = e & 131071;
    int row = rem >> 7, col = rem & 127;
    int h = hb >> 2, bb = hb & 3;
    float inv = 1.0f / lf32[hb * 1024 + row];
    float4 v = *(const float4*)(Of32 + e);
    short4 o;
    o.x = f2bf(v.x * inv); o.y = f2bf(v.y * inv);
    o.z = f2bf(v.z * inv); o.w = f2bf(v.w * inv);
    *(short4*)(Ocat + (size_t)(bb * TT + 1024 + row) * HIDDEN + h * HDIM + col) = o;
}

// ---------------- kernel 4: output projection (128x128, global_load_lds) ----------------
__global__ __launch_bounds__(256) void out_gemm(
    const short* __restrict__ A, const short* __restrict__ Bt, float* __restrict__ out)
{
    __shared__ short Ash[128 * 32];
    __shared__ short Bsh[128 * 32];
    const int m0 = blockIdx.x * 128;
    const int n0 = blockIdx.y * 128;

    const int tid = threadIdx.x;
    const int wave = tid >> 6, lane = tid & 63;
    const int quad = lane >> 4, l16 = lane & 15;
    const int wm = (wave >> 1) * 64, wn = (wave & 1) * 64;

    f32x4 acc[4][4] = {};

    const int r0 = tid >> 2, cc0 = (tid & 3) * 8;
    const int r1 = r0 + 64;
    short* adst0 = Ash + wave * 512;
    short* adst1 = Ash + 2048 + wave * 512;
    short* bdst0 = Bsh + wave * 512;
    short* bdst1 = Bsh + 2048 + wave * 512;
    const short* asrc0 = A + (size_t)(m0 + r0) * HIDDEN + cc0;
    const short* asrc1 = A + (size_t)(m0 + r1) * HIDDEN + cc0;
    const short* bsrc0 = Bt + (size_t)(n0 + r0) * HIDDEN + cc0;
    const short* bsrc1 = Bt + (size_t)(n0 + r1) * HIDDEN + cc0;

    for (int k0 = 0; k0 < HIDDEN; k0 += 32) {
        __syncthreads();
        gll16(asrc0 + k0, adst0);
        gll16(asrc1 + k0, adst1);
        gll16(bsrc0 + k0, bdst0);
        gll16(bsrc1 + k0, bdst1);
        __syncthreads();
        bf16x8 af[4], bfr[4];
        for (int mi = 0; mi < 4; mi++)
            af[mi] = *(const bf16x8*)(Ash + (wm + mi * 16 + l16) * 32 + quad * 8);
        for (int ni = 0; ni < 4; ni++)
            bfr[ni] = *(const bf16x8*)(Bsh + (wn + ni * 16 + l16) * 32 + quad * 8);
        for (int mi = 0; mi < 4; mi++)
            for (int ni = 0; ni < 4; ni++)
                acc[mi][ni] = __builtin_amdgcn_mfma_f32_16x16x32_bf16(af[mi], bfr[ni], acc[mi][ni], 0, 0, 0);
    }

    for (int mi = 0; mi < 4; mi++)
        for (int ni = 0; ni < 4; ni++)
            for (int r = 0; r < 4; r++) {
                int m = m0 + wm + mi * 16 + quad * 4 + r;
                int n = n0 + wn + ni * 16 + l16;
                out[(size_t)m * HIDDEN + n] = acc[mi][ni][r];
            }
}

extern "C" void kernel_launch(void* const* d_in, const int* in_sizes, int n_in,
                              void* d_out, int out_size, void* d_ws, size_t ws_size,
                              hipStream_t stream) {
    (void)in_sizes; (void)n_in; (void)out_size; (void)ws_size;
    const float* x  = (const float*)d_in[0];
    const float* Wq = (const float*)d_in[1];
    const float* Wk = (const float*)d_in[2];
    const float* Wv = (const float*)d_in[3];
    const float* Wo = (const float*)d_in[4];
    const int* iscp = (const int*)d_in[5];
    float* out = (float*)d_out;

    short* xb   = (short*)d_ws;                       // 8192*896 shorts
    short* Qb   = xb   + (size_t)MTOT * HIDDEN;       // 7*8192*128 each
    short* Kb   = Qb   + (size_t)HEADS * MTOT * HDIM;
    short* Vtb  = Kb   + (size_t)HEADS * MTOT * HDIM;
    short* Ocat = Vtb  + (size_t)HEADS * MTOT * HDIM; // 8192*896 (aliased with Wt)
    short* Wt   = Ocat;                               // 21*128*896, used only before attn
    short* Wob  = Ocat + (size_t)MTOT * HIDDEN;       // 896*896
    // split-S accumulators: Of32 aliases xb (dead after qkv_gemm); exact same byte size.
    float* Of32 = (float*)d_ws;                       // 7*4*1024*128 floats = 14.68 MB
    float* lf32 = (float*)(Wob + (size_t)HIDDEN * HIDDEN);  // 7*4*1024 floats

    cast_x_kernel<<<(MTOT * HIDDEN) / (256 * 4), 256, 0, stream>>>(x, xb);
    cast_wo_kernel<<<(HIDDEN * HIDDEN) / (256 * 4), 256, 0, stream>>>(Wo, Wob);
    transpose_cast_w<<<dim3(HIDDEN / 32, HDIM / 32, 21), 256, 0, stream>>>(Wq, Wk, Wv, Wt);
    qkv_gemm<<<dim3(MTOT / 128, 21), 256, 0, stream>>>(xb, Wt, Qb, Kb, Vtb);
    zero_acc<<<(OF32_N / 4 + 255) / 256, 256, 0, stream>>>(Of32, lf32);
    fano_attn<<<dim3(TT / 128, 8, BB * HEADS), 256, 0, stream>>>(Qb, Kb, Vtb, Ocat, Of32, lf32, iscp);
    attn_norm<<<(OF32_N / 4) / 256, 256, 0, stream>>>(Of32, lf32, Ocat);
    out_gemm<<<dim3(MTOT / 128, HIDDEN / 128), 256, 0, stream>>>(Ocat, Wob, out);
}

// Round 2
// 456.264 us; speedup vs baseline: 1.5856x; 1.5856x over previous
//
#include <hip/hip_runtime.h>
#include <hip/hip_bf16.h>

#define HIDDEN 896
#define HEADS 7
#define HDIM 128
#define BB 4
#define TT 2048
#define MTOT (BB*TT)   // 8192

typedef short bf16x8 __attribute__((ext_vector_type(8)));
typedef float f32x4 __attribute__((ext_vector_type(4)));

__device__ __forceinline__ short f2bf(float f) {
    union { float f; unsigned u; } v; v.f = f;
    unsigned r = (v.u + 0x7FFF + ((v.u >> 16) & 1)) >> 16;
    return (short)r;
}

// async global->LDS, 16B per lane; lds dst must be wave-uniform base (+lane*16 implicit)
__device__ __forceinline__ void gll16(const short* g, short* l) {
    __builtin_amdgcn_global_load_lds(
        (const __attribute__((address_space(1))) unsigned int*)g,
        (__attribute__((address_space(3))) unsigned int*)l, 16, 0, 0);
}

// ---------------- kernel 1: cast x (fp32) -> bf16 ----------------
__global__ __launch_bounds__(256) void cast_x_kernel(const float* __restrict__ x,
                                                     short* __restrict__ xb) {
    int base = (blockIdx.x * 256 + threadIdx.x) * 4;
    if (base < MTOT * HIDDEN) {
        float4 v = *(const float4*)(x + base);
        short4 o;
        o.x = f2bf(v.x); o.y = f2bf(v.y); o.z = f2bf(v.z); o.w = f2bf(v.w);
        *(short4*)(xb + base) = o;
    }
}

// cast Wo fp32[896][896] -> bf16 (already B^T form [n][k])
__global__ __launch_bounds__(256) void cast_wo_kernel(const float* __restrict__ src,
                                                      short* __restrict__ dst) {
    int base = (blockIdx.x * 256 + threadIdx.x) * 4;
    if (base < HIDDEN * HIDDEN) {
        float4 v = *(const float4*)(src + base);
        short4 o;
        o.x = f2bf(v.x); o.y = f2bf(v.y); o.z = f2bf(v.z); o.w = f2bf(v.w);
        *(short4*)(dst + base) = o;
    }
}

// transpose-cast Wq/Wk/Wv fp32 [head][896 k][128 n] -> bf16 Wt[type*7+head][128 n][896 k]
__global__ __launch_bounds__(256) void transpose_cast_w(
    const float* __restrict__ Wq, const float* __restrict__ Wk,
    const float* __restrict__ Wv, short* __restrict__ Wt)
{
    __shared__ float tile[32][33];
    const int z = blockIdx.z;
    const int type = z / 7, head = z % 7;
    const float* src = (type == 0 ? Wq : (type == 1 ? Wk : Wv)) + head * (HIDDEN * HDIM);
    short* dst = Wt + (size_t)z * (HDIM * HIDDEN);
    const int r0 = blockIdx.x * 32, c0 = blockIdx.y * 32;
    const int tx = threadIdx.x & 31, ty = threadIdx.x >> 5;  // 32 x 8
    for (int i = 0; i < 4; i++)
        tile[ty * 4 + i][tx] = src[(r0 + ty * 4 + i) * HDIM + c0 + tx];
    __syncthreads();
    for (int i = 0; i < 4; i++)
        dst[(c0 + ty * 4 + i) * HIDDEN + r0 + tx] = f2bf(tile[tx][ty * 4 + i]);
}

// ---------------- kernel 2: QKV projection GEMM (128x128, global_load_lds) ----------------
__global__ __launch_bounds__(256) void qkv_gemm(
    const short* __restrict__ xb, const short* __restrict__ Wt,
    short* __restrict__ Q, short* __restrict__ Kk, short* __restrict__ Vt)
{
    __shared__ short Ash[128 * 32];
    __shared__ short Bsh[128 * 32];
    const int m0 = blockIdx.x * 128;
    const int z = blockIdx.y;
    const int head = z % 7, type = z / 7;
    const short* Wz = Wt + (size_t)z * (HDIM * HIDDEN);

    const int tid = threadIdx.x;
    const int wave = tid >> 6, lane = tid & 63;
    const int quad = lane >> 4, l16 = lane & 15;
    const int wm = (wave >> 1) * 64, wn = (wave & 1) * 64;

    f32x4 acc[4][4] = {};

    const int r0 = tid >> 2, cc0 = (tid & 3) * 8;
    const int r1 = r0 + 64;
    short* adst0 = Ash + wave * 512;
    short* adst1 = Ash + 2048 + wave * 512;
    short* bdst0 = Bsh + wave * 512;
    short* bdst1 = Bsh + 2048 + wave * 512;
    const short* asrc0 = xb + (size_t)(m0 + r0) * HIDDEN + cc0;
    const short* asrc1 = xb + (size_t)(m0 + r1) * HIDDEN + cc0;
    const short* bsrc0 = Wz + (size_t)r0 * HIDDEN + cc0;
    const short* bsrc1 = Wz + (size_t)r1 * HIDDEN + cc0;

    for (int k0 = 0; k0 < HIDDEN; k0 += 32) {
        __syncthreads();                 // prev tile fully consumed
        gll16(asrc0 + k0, adst0);
        gll16(asrc1 + k0, adst1);
        gll16(bsrc0 + k0, bdst0);
        gll16(bsrc1 + k0, bdst1);
        __syncthreads();                 // drains vmcnt -> LDS tile ready
        bf16x8 af[4], bfr[4];
        for (int mi = 0; mi < 4; mi++)
            af[mi] = *(const bf16x8*)(Ash + (wm + mi * 16 + l16) * 32 + quad * 8);
        for (int ni = 0; ni < 4; ni++)
            bfr[ni] = *(const bf16x8*)(Bsh + (wn + ni * 16 + l16) * 32 + quad * 8);
        for (int mi = 0; mi < 4; mi++)
            for (int ni = 0; ni < 4; ni++)
                acc[mi][ni] = __builtin_amdgcn_mfma_f32_16x16x32_bf16(af[mi], bfr[ni], acc[mi][ni], 0, 0, 0);
    }

    const size_t base = (size_t)head * (MTOT * HDIM);
    if (type == 0) {
        // fold softmax scale AND log2(e) into Q (softmax done in exp2 domain)
        const float qs = 0.08838834764831845f * 1.4426950408889634f;
        for (int mi = 0; mi < 4; mi++)
            for (int ni = 0; ni < 4; ni++)
                for (int r = 0; r < 4; r++) {
                    int m = m0 + wm + mi * 16 + quad * 4 + r;
                    int n = wn + ni * 16 + l16;
                    Q[base + (size_t)m * HDIM + n] = f2bf(acc[mi][ni][r] * qs);
                }
    } else if (type == 1) {
        for (int mi = 0; mi < 4; mi++)
            for (int ni = 0; ni < 4; ni++)
                for (int r = 0; r < 4; r++) {
                    int m = m0 + wm + mi * 16 + quad * 4 + r;
                    int n = wn + ni * 16 + l16;
                    Kk[base + (size_t)m * HDIM + n] = f2bf(acc[mi][ni][r]);
                }
    } else {
        for (int mi = 0; mi < 4; mi++)
            for (int ni = 0; ni < 4; ni++) {
                int m = m0 + wm + mi * 16 + quad * 4;
                int bb = m >> 11, t = m & 2047;
                int n = wn + ni * 16 + l16;
                short4 o;
                o.x = f2bf(acc[mi][ni][0]); o.y = f2bf(acc[mi][ni][1]);
                o.z = f2bf(acc[mi][ni][2]); o.w = f2bf(acc[mi][ni][3]);
                *(short4*)(Vt + base + (size_t)bb * (HDIM * TT) + (size_t)n * TT + t) = o;
            }
    }
}

// ---------------- kernel 3: fano flash attention v10 ----------------
// No K/V LDS staging: K and V tiles are L2-resident (1 MB per (b,h)), and the MFMA
// B-fragment loads are contiguous 16B chunks directly addressable in global memory.
// This removes 2/3 of LDS traffic AND both per-step __syncthreads (the only remaining
// LDS buffer, Ps, is wave-private), so the 4 waves run fully independently.
__global__ __launch_bounds__(256) void fano_attn(
    const short* __restrict__ Q, const short* __restrict__ K, const short* __restrict__ Vt,
    short* __restrict__ Ocat, const int* __restrict__ iscp)
{
    __shared__ short Ps[4][32 * 72];   // wave-private P transpose buffer

    const int causal = *iscp;
    const int q0 = blockIdx.x * 128;
    const int b = blockIdx.y, h = blockIdx.z;
    const int tid = threadIdx.x, wave = tid >> 6, lane = tid & 63;
    const int quad = lane >> 4, l16 = lane & 15;
    const int iw = q0 + wave * 32;   // wave's min q-row

    const short* Qb = Q + (size_t)(h * MTOT + b * TT + q0) * HDIM;
    const short* Kb = K + (size_t)(h * MTOT + b * TT) * HDIM;
    const short* Vb = Vt + (size_t)h * MTOT * HDIM + (size_t)b * HDIM * TT;

    bf16x8 qf[2][4];
    for (int g = 0; g < 2; g++)
        for (int ks = 0; ks < 4; ks++)
            qf[g][ks] = *(const bf16x8*)(Qb + (size_t)(wave * 32 + g * 16 + l16) * HDIM + ks * 32 + quad * 8);

    f32x4 oacc[2][8] = {};
    f32x4 lacc[2] = {};
    int irow[2][4];
    for (int g = 0; g < 2; g++)
        for (int r = 0; r < 4; r++)
            irow[g][r] = q0 + wave * 32 + g * 16 + quad * 4 + r;

    const bf16x8 vones = {0x3F80, 0x3F80, 0x3F80, 0x3F80, 0x3F80, 0x3F80, 0x3F80, 0x3F80};

    const int send = causal ? (q0 + 128) : TT;
    int d7b = (l16 - h + 7) % 7;
    short* Pw = &Ps[wave][0];

    for (int s0 = 0; s0 < send; s0 += 64) {
        // ---- QK^T: B-fragments straight from global (L2-hot) ----
        const short* Ks0 = Kb + (size_t)s0 * HDIM;
        f32x4 sacc[2][4] = {};
        for (int ni = 0; ni < 4; ni++)
            for (int ks = 0; ks < 4; ks++) {
                bf16x8 bk = *(const bf16x8*)(Ks0 + (size_t)(ni * 16 + l16) * HDIM + ks * 32 + quad * 8);
                sacc[0][ni] = __builtin_amdgcn_mfma_f32_16x16x32_bf16(qf[0][ks], bk, sacc[0][ni], 0, 0, 0);
                sacc[1][ni] = __builtin_amdgcn_mfma_f32_16x16x32_bf16(qf[1][ks], bk, sacc[1][ni], 0, 0, 0);
            }

        // ---- mask + exp2 ----
        const bool full = (s0 + 80 > iw) && (causal || (s0 < iw + 48));
        if (full) {
            for (int ni = 0; ni < 4; ni++) {
                int d7 = d7b + 2 * ni; if (d7 >= 7) d7 -= 7;
                bool line = (0x0B >> d7) & 1;
                int s = s0 + ni * 16 + l16;
                for (int g = 0; g < 2; g++)
                    for (int r = 0; r < 4; r++) {
                        int i = irow[g][r];
                        bool ok = causal ? ((s <= i) & (line | (s >= i - 16)))
                                         : (line | ((s >= i - 16) & (s <= i + 16)));
                        sacc[g][ni][r] = ok ? exp2f(sacc[g][ni][r]) : 0.0f;
                    }
            }
        } else {
            for (int ni = 0; ni < 4; ni++) {
                int d7 = d7b + 2 * ni; if (d7 >= 7) d7 -= 7;
                bool line = (0x0B >> d7) & 1;
                for (int g = 0; g < 2; g++)
                    for (int r = 0; r < 4; r++)
                        sacc[g][ni][r] = line ? exp2f(sacc[g][ni][r]) : 0.0f;
            }
        }
        d7b++; if (d7b == 7) d7b = 0;

        // ---- P transpose through wave-private LDS (no barrier: same-wave dependency) ----
        for (int g = 0; g < 2; g++)
            for (int ni = 0; ni < 4; ni++)
                for (int r = 0; r < 4; r++)
                    Pw[(g * 16 + quad * 4 + r) * 72 + ni * 16 + l16] = f2bf(sacc[g][ni][r]);

        // ---- PV + row-sum: V fragments straight from global (L2-hot) ----
        for (int ks2 = 0; ks2 < 2; ks2++) {
            bf16x8 ap0 = *(const bf16x8*)(Pw + l16 * 72 + ks2 * 32 + quad * 8);
            bf16x8 ap1 = *(const bf16x8*)(Pw + (16 + l16) * 72 + ks2 * 32 + quad * 8);
            lacc[0] = __builtin_amdgcn_mfma_f32_16x16x32_bf16(ap0, vones, lacc[0], 0, 0, 0);
            lacc[1] = __builtin_amdgcn_mfma_f32_16x16x32_bf16(ap1, vones, lacc[1], 0, 0, 0);
            for (int nj = 0; nj < 8; nj++) {
                bf16x8 bv = *(const bf16x8*)(Vb + (size_t)(nj * 16 + l16) * TT + s0 + ks2 * 32 + quad * 8);
                oacc[0][nj] = __builtin_amdgcn_mfma_f32_16x16x32_bf16(ap0, bv, oacc[0][nj], 0, 0, 0);
                oacc[1][nj] = __builtin_amdgcn_mfma_f32_16x16x32_bf16(ap1, bv, oacc[1][nj], 0, 0, 0);
            }
        }
    }

    short* Obase = Ocat + (size_t)(b * TT) * HIDDEN + h * HDIM;
    for (int g = 0; g < 2; g++) {
        float inv[4];
        for (int r = 0; r < 4; r++) inv[r] = 1.0f / lacc[g][r];
        for (int nj = 0; nj < 8; nj++)
            for (int r = 0; r < 4; r++)
                Obase[(size_t)irow[g][r] * HIDDEN + nj * 16 + l16] = f2bf(oacc[g][nj][r] * inv[r]);
    }
}

// ---------------- kernel 4: output projection (128x128, global_load_lds) ----------------
__global__ __launch_bounds__(256) void out_gemm(
    const short* __restrict__ A, const short* __restrict__ Bt, float* __restrict__ out)
{
    __shared__ short Ash[128 * 32];
    __shared__ short Bsh[128 * 32];
    const int m0 = blockIdx.x * 128;
    const int n0 = blockIdx.y * 128;

    const int tid = threadIdx.x;
    const int wave = tid >> 6, lane = tid & 63;
    const int quad = lane >> 4, l16 = lane & 15;
    const int wm = (wave >> 1) * 64, wn = (wave & 1) * 64;

    f32x4 acc[4][4] = {};

    const int r0 = tid >> 2, cc0 = (tid & 3) * 8;
    const int r1 = r0 + 64;
    short* adst0 = Ash + wave * 512;
    short* adst1 = Ash + 2048 + wave * 512;
    short* bdst0 = Bsh + wave * 512;
    short* bdst1 = Bsh + 2048 + wave * 512;
    const short* asrc0 = A + (size_t)(m0 + r0) * HIDDEN + cc0;
    const short* asrc1 = A + (size_t)(m0 + r1) * HIDDEN + cc0;
    const short* bsrc0 = Bt + (size_t)(n0 + r0) * HIDDEN + cc0;
    const short* bsrc1 = Bt + (size_t)(n0 + r1) * HIDDEN + cc0;

    for (int k0 = 0; k0 < HIDDEN; k0 += 32) {
        __syncthreads();
        gll16(asrc0 + k0, adst0);
        gll16(asrc1 + k0, adst1);
        gll16(bsrc0 + k0, bdst0);
        gll16(bsrc1 + k0, bdst1);
        __syncthreads();
        bf16x8 af[4], bfr[4];
        for (int mi = 0; mi < 4; mi++)
            af[mi] = *(const bf16x8*)(Ash + (wm + mi * 16 + l16) * 32 + quad * 8);
        for (int ni = 0; ni < 4; ni++)
            bfr[ni] = *(const bf16x8*)(Bsh + (wn + ni * 16 + l16) * 32 + quad * 8);
        for (int mi = 0; mi < 4; mi++)
            for (int ni = 0; ni < 4; ni++)
                acc[mi][ni] = __builtin_amdgcn_mfma_f32_16x16x32_bf16(af[mi], bfr[ni], acc[mi][ni], 0, 0, 0);
    }

    for (int mi = 0; mi < 4; mi++)
        for (int ni = 0; ni < 4; ni++)
            for (int r = 0; r < 4; r++) {
                int m = m0 + wm + mi * 16 + quad * 4 + r;
                int n = n0 + wn + ni * 16 + l16;
                out[(size_t)m * HIDDEN + n] = acc[mi][ni][r];
            }
}

extern "C" void kernel_launch(void* const* d_in, const int* in_sizes, int n_in,
                              void* d_out, int out_size, void* d_ws, size_t ws_size,
                              hipStream_t stream) {
    (void)in_sizes; (void)n_in; (void)out_size; (void)ws_size;
    const float* x  = (const float*)d_in[0];
    const float* Wq = (const float*)d_in[1];
    const float* Wk = (const float*)d_in[2];
    const float* Wv = (const float*)d_in[3];
    const float* Wo = (const float*)d_in[4];
    const int* iscp = (const int*)d_in[5];
    float* out = (float*)d_out;

    short* xb   = (short*)d_ws;                       // 8192*896
    short* Qb   = xb   + (size_t)MTOT * HIDDEN;       // 7*8192*128 each
    short* Kb   = Qb   + (size_t)HEADS * MTOT * HDIM;
    short* Vtb  = Kb   + (size_t)HEADS * MTOT * HDIM;
    short* Ocat = Vtb  + (size_t)HEADS * MTOT * HDIM; // 8192*896 (aliased with Wt)
    short* Wt   = Ocat;                               // 21*128*896, used only before attn
    short* Wob  = Ocat + (size_t)MTOT * HIDDEN;       // 896*896

    cast_x_kernel<<<(MTOT * HIDDEN) / (256 * 4), 256, 0, stream>>>(x, xb);
    cast_wo_kernel<<<(HIDDEN * HIDDEN) / (256 * 4), 256, 0, stream>>>(Wo, Wob);
    transpose_cast_w<<<dim3(HIDDEN / 32, HDIM / 32, 21), 256, 0, stream>>>(Wq, Wk, Wv, Wt);
    qkv_gemm<<<dim3(MTOT / 128, 21), 256, 0, stream>>>(xb, Wt, Qb, Kb, Vtb);
    fano_attn<<<dim3(TT / 128, BB, HEADS), 256, 0, stream>>>(Qb, Kb, Vtb, Ocat, iscp);
    out_gemm<<<dim3(MTOT / 128, HIDDEN / 128), 256, 0, stream>>>(Ocat, Wob, out);
}

// Round 3
// 356.228 us; speedup vs baseline: 2.0308x; 1.2808x over previous
//
#include <hip/hip_runtime.h>
#include <hip/hip_bf16.h>

#define HIDDEN 896
#define HEADS 7
#define HDIM 128
#define BB 4
#define TT 2048
#define MTOT (BB*TT)   // 8192

// LDS strides (shorts). 132/68 give 4-way-max bank aliasing (vs 8-way at 136/72)
// and total LDS 51,712 B < 53,248 (160K/3) -> 3 blocks/CU (VGPR 144 also allows 3).
#define KSP 132
#define VSP 68
#define PSP 68

typedef short bf16x8 __attribute__((ext_vector_type(8)));
typedef float f32x4 __attribute__((ext_vector_type(4)));

__device__ __forceinline__ short f2bf(float f) {
    union { float f; unsigned u; } v; v.f = f;
    unsigned r = (v.u + 0x7FFF + ((v.u >> 16) & 1)) >> 16;
    return (short)r;
}

// async global->LDS, 16B per lane; lds dst must be wave-uniform base (+lane*16 implicit)
__device__ __forceinline__ void gll16(const short* g, short* l) {
    __builtin_amdgcn_global_load_lds(
        (const __attribute__((address_space(1))) unsigned int*)g,
        (__attribute__((address_space(3))) unsigned int*)l, 16, 0, 0);
}

// ---------------- kernel 1: cast x (fp32) -> bf16 ----------------
__global__ __launch_bounds__(256) void cast_x_kernel(const float* __restrict__ x,
                                                     short* __restrict__ xb) {
    int base = (blockIdx.x * 256 + threadIdx.x) * 4;
    if (base < MTOT * HIDDEN) {
        float4 v = *(const float4*)(x + base);
        short4 o;
        o.x = f2bf(v.x); o.y = f2bf(v.y); o.z = f2bf(v.z); o.w = f2bf(v.w);
        *(short4*)(xb + base) = o;
    }
}

// cast Wo fp32[896][896] -> bf16 (already B^T form [n][k])
__global__ __launch_bounds__(256) void cast_wo_kernel(const float* __restrict__ src,
                                                      short* __restrict__ dst) {
    int base = (blockIdx.x * 256 + threadIdx.x) * 4;
    if (base < HIDDEN * HIDDEN) {
        float4 v = *(const float4*)(src + base);
        short4 o;
        o.x = f2bf(v.x); o.y = f2bf(v.y); o.z = f2bf(v.z); o.w = f2bf(v.w);
        *(short4*)(dst + base) = o;
    }
}

// transpose-cast Wq/Wk/Wv fp32 [head][896 k][128 n] -> bf16 Wt[type*7+head][128 n][896 k]
__global__ __launch_bounds__(256) void transpose_cast_w(
    const float* __restrict__ Wq, const float* __restrict__ Wk,
    const float* __restrict__ Wv, short* __restrict__ Wt)
{
    __shared__ float tile[32][33];
    const int z = blockIdx.z;
    const int type = z / 7, head = z % 7;
    const float* src = (type == 0 ? Wq : (type == 1 ? Wk : Wv)) + head * (HIDDEN * HDIM);
    short* dst = Wt + (size_t)z * (HDIM * HIDDEN);
    const int r0 = blockIdx.x * 32, c0 = blockIdx.y * 32;
    const int tx = threadIdx.x & 31, ty = threadIdx.x >> 5;  // 32 x 8
    for (int i = 0; i < 4; i++)
        tile[ty * 4 + i][tx] = src[(r0 + ty * 4 + i) * HDIM + c0 + tx];
    __syncthreads();
    for (int i = 0; i < 4; i++)
        dst[(c0 + ty * 4 + i) * HIDDEN + r0 + tx] = f2bf(tile[tx][ty * 4 + i]);
}

// ---------------- kernel 2: QKV projection GEMM (128x128, global_load_lds) ----------------
// grid (21 z, 64 m): x=z fastest so dispatch-consecutive blocks share the same A m-tile
// (229 KB, L2-hot) and the 21 B panels (4.8 MB total) stay resident across m-groups.
__global__ __launch_bounds__(256) void qkv_gemm(
    const short* __restrict__ xb, const short* __restrict__ Wt,
    short* __restrict__ Q, short* __restrict__ Kk, short* __restrict__ Vt)
{
    __shared__ short Ash[128 * 32];
    __shared__ short Bsh[128 * 32];
    const int z = blockIdx.x;
    const int m0 = blockIdx.y * 128;
    const int head = z % 7, type = z / 7;
    const short* Wz = Wt + (size_t)z * (HDIM * HIDDEN);

    const int tid = threadIdx.x;
    const int wave = tid >> 6, lane = tid & 63;
    const int quad = lane >> 4, l16 = lane & 15;
    const int wm = (wave >> 1) * 64, wn = (wave & 1) * 64;

    f32x4 acc[4][4] = {};

    const int r0 = tid >> 2, cc0 = (tid & 3) * 8;
    const int r1 = r0 + 64;
    short* adst0 = Ash + wave * 512;
    short* adst1 = Ash + 2048 + wave * 512;
    short* bdst0 = Bsh + wave * 512;
    short* bdst1 = Bsh + 2048 + wave * 512;
    const short* asrc0 = xb + (size_t)(m0 + r0) * HIDDEN + cc0;
    const short* asrc1 = xb + (size_t)(m0 + r1) * HIDDEN + cc0;
    const short* bsrc0 = Wz + (size_t)r0 * HIDDEN + cc0;
    const short* bsrc1 = Wz + (size_t)r1 * HIDDEN + cc0;

    for (int k0 = 0; k0 < HIDDEN; k0 += 32) {
        __syncthreads();                 // prev tile fully consumed
        gll16(asrc0 + k0, adst0);
        gll16(asrc1 + k0, adst1);
        gll16(bsrc0 + k0, bdst0);
        gll16(bsrc1 + k0, bdst1);
        __syncthreads();                 // drains vmcnt -> LDS tile ready
        bf16x8 af[4], bfr[4];
        for (int mi = 0; mi < 4; mi++)
            af[mi] = *(const bf16x8*)(Ash + (wm + mi * 16 + l16) * 32 + quad * 8);
        for (int ni = 0; ni < 4; ni++)
            bfr[ni] = *(const bf16x8*)(Bsh + (wn + ni * 16 + l16) * 32 + quad * 8);
        for (int mi = 0; mi < 4; mi++)
            for (int ni = 0; ni < 4; ni++)
                acc[mi][ni] = __builtin_amdgcn_mfma_f32_16x16x32_bf16(af[mi], bfr[ni], acc[mi][ni], 0, 0, 0);
    }

    const size_t base = (size_t)head * (MTOT * HDIM);
    if (type == 0) {
        // fold softmax scale AND log2(e) into Q (softmax done in exp2 domain)
        const float qs = 0.08838834764831845f * 1.4426950408889634f;
        for (int mi = 0; mi < 4; mi++)
            for (int ni = 0; ni < 4; ni++)
                for (int r = 0; r < 4; r++) {
                    int m = m0 + wm + mi * 16 + quad * 4 + r;
                    int n = wn + ni * 16 + l16;
                    Q[base + (size_t)m * HDIM + n] = f2bf(acc[mi][ni][r] * qs);
                }
    } else if (type == 1) {
        for (int mi = 0; mi < 4; mi++)
            for (int ni = 0; ni < 4; ni++)
                for (int r = 0; r < 4; r++) {
                    int m = m0 + wm + mi * 16 + quad * 4 + r;
                    int n = wn + ni * 16 + l16;
                    Kk[base + (size_t)m * HDIM + n] = f2bf(acc[mi][ni][r]);
                }
    } else {
        for (int mi = 0; mi < 4; mi++)
            for (int ni = 0; ni < 4; ni++) {
                int m = m0 + wm + mi * 16 + quad * 4;
                int bb = m >> 11, t = m & 2047;
                int n = wn + ni * 16 + l16;
                short4 o;
                o.x = f2bf(acc[mi][ni][0]); o.y = f2bf(acc[mi][ni][1]);
                o.z = f2bf(acc[mi][ni][2]); o.w = f2bf(acc[mi][ni][3]);
                *(short4*)(Vt + base + (size_t)bb * (HDIM * TT) + (size_t)n * TT + t) = o;
            }
    }
}

// ---------------- kernel 3: fano flash attention v11 ----------------
// Round-0 staging/prefetch structure (proven) with:
//  - LDS pads 132/68: 51,712 B -> 3 blocks/CU (was 54,272 -> 2), 4-way max bank alias.
//  - causal split-S: qt>=12 split into 2 chunks writing deterministic f32 partials
//    (no atomics) into buffers aliasing dead xb; merged by attn_merge.
__global__ __launch_bounds__(256) void fano_attn(
    const short* __restrict__ Q, const short* __restrict__ K, const short* __restrict__ Vt,
    short* __restrict__ Ocat, float* __restrict__ Opart, float* __restrict__ lpart,
    const int* __restrict__ iscp)
{
    __shared__ short Ks[64 * KSP];
    __shared__ short Vs[128 * VSP];
    __shared__ short Ps[4][32 * PSP];

    const int causal = *iscp;
    const int bh = blockIdx.x;
    const int b = bh & 3, h = bh >> 2;
    const int qt = blockIdx.y;
    const int ck = blockIdx.z;
    const int q0 = qt * 128;

    const bool split = causal && (qt >= 12);
    if (ck == 1 && !split) return;
    const int ns = causal ? (qt * 2 + 2) : (TT / 64);
    const int step_lo = (split && ck) ? (ns / 2) : 0;
    const int step_hi = (split && !ck) ? (ns / 2) : ns;
    const int s_init = step_lo * 64;
    const int send = step_hi * 64;

    const int tid = threadIdx.x, wave = tid >> 6, lane = tid & 63;
    const int quad = lane >> 4, l16 = lane & 15;
    const int iw = q0 + wave * 32;   // wave's min q-row

    const short* Qb = Q + (size_t)(h * MTOT + b * TT + q0) * HDIM;
    const short* Kb = K + (size_t)(h * MTOT + b * TT) * HDIM;
    const short* Vb = Vt + (size_t)h * MTOT * HDIM + (size_t)b * HDIM * TT;

    bf16x8 qf[2][4];
    for (int g = 0; g < 2; g++)
        for (int ks = 0; ks < 4; ks++)
            qf[g][ks] = *(const bf16x8*)(Qb + (size_t)(wave * 32 + g * 16 + l16) * HDIM + ks * 32 + quad * 8);

    f32x4 oacc[2][8] = {};
    f32x4 lacc[2] = {};
    int irow[2][4];
    for (int g = 0; g < 2; g++)
        for (int r = 0; r < 4; r++)
            irow[g][r] = q0 + wave * 32 + g * 16 + quad * 4 + r;

    const bf16x8 vones = {0x3F80, 0x3F80, 0x3F80, 0x3F80, 0x3F80, 0x3F80, 0x3F80, 0x3F80};

    int krow[4], kcol[4], vrow[4], vcol[4];
    for (int i = 0; i < 4; i++) {
        int c = tid + i * 256;
        krow[i] = c >> 4; kcol[i] = (c & 15) * 8;
        vrow[i] = c >> 3; vcol[i] = (c & 7) * 8;
    }

    bf16x8 kreg[4], vreg[4];
    for (int i = 0; i < 4; i++) {
        kreg[i] = *(const bf16x8*)(Kb + (size_t)(s_init + krow[i]) * HDIM + kcol[i]);
        vreg[i] = *(const bf16x8*)(Vb + (size_t)vrow[i] * TT + s_init + vcol[i]);
    }

    int d7b = (l16 - h + 7 + step_lo) % 7;
    short* Pw = &Ps[wave][0];

    for (int s0 = s_init; s0 < send; s0 += 64) {
        __syncthreads();
        for (int i = 0; i < 4; i++) {
            *(bf16x8*)(Ks + krow[i] * KSP + kcol[i]) = kreg[i];
            *(bf16x8*)(Vs + vrow[i] * VSP + vcol[i]) = vreg[i];
        }
        __syncthreads();

        int sn = s0 + 64; if (sn >= send) sn = s0;
        const short* Kn = Kb + (size_t)sn * HDIM;
        const short* Vn = Vb + sn;
        for (int i = 0; i < 4; i++) {
            kreg[i] = *(const bf16x8*)(Kn + (size_t)krow[i] * HDIM + kcol[i]);
            vreg[i] = *(const bf16x8*)(Vn + (size_t)vrow[i] * TT + vcol[i]);
        }

        f32x4 sacc[2][4] = {};
        for (int ni = 0; ni < 4; ni++)
            for (int ks = 0; ks < 4; ks++) {
                bf16x8 bk = *(const bf16x8*)(Ks + (ni * 16 + l16) * KSP + ks * 32 + quad * 8);
                sacc[0][ni] = __builtin_amdgcn_mfma_f32_16x16x32_bf16(qf[0][ks], bk, sacc[0][ni], 0, 0, 0);
                sacc[1][ni] = __builtin_amdgcn_mfma_f32_16x16x32_bf16(qf[1][ks], bk, sacc[1][ni], 0, 0, 0);
            }

        const bool full = (s0 + 80 > iw) && (causal || (s0 < iw + 48));
        if (full) {
            for (int ni = 0; ni < 4; ni++) {
                int d7 = d7b + 2 * ni; if (d7 >= 7) d7 -= 7;
                bool line = (0x0B >> d7) & 1;
                int s = s0 + ni * 16 + l16;
                for (int g = 0; g < 2; g++)
                    for (int r = 0; r < 4; r++) {
                        int i = irow[g][r];
                        bool ok = causal ? ((s <= i) & (line | (s >= i - 16)))
                                         : (line | ((s >= i - 16) & (s <= i + 16)));
                        sacc[g][ni][r] = ok ? exp2f(sacc[g][ni][r]) : 0.0f;
                    }
            }
        } else {
            for (int ni = 0; ni < 4; ni++) {
                int d7 = d7b + 2 * ni; if (d7 >= 7) d7 -= 7;
                bool line = (0x0B >> d7) & 1;
                for (int g = 0; g < 2; g++)
                    for (int r = 0; r < 4; r++)
                        sacc[g][ni][r] = line ? exp2f(sacc[g][ni][r]) : 0.0f;
            }
        }
        d7b++; if (d7b == 7) d7b = 0;

        for (int g = 0; g < 2; g++)
            for (int ni = 0; ni < 4; ni++)
                for (int r = 0; r < 4; r++)
                    Pw[(g * 16 + quad * 4 + r) * PSP + ni * 16 + l16] = f2bf(sacc[g][ni][r]);

        for (int ks2 = 0; ks2 < 2; ks2++) {
            bf16x8 ap0 = *(const bf16x8*)(Pw + l16 * PSP + ks2 * 32 + quad * 8);
            bf16x8 ap1 = *(const bf16x8*)(Pw + (16 + l16) * PSP + ks2 * 32 + quad * 8);
            lacc[0] = __builtin_amdgcn_mfma_f32_16x16x32_bf16(ap0, vones, lacc[0], 0, 0, 0);
            lacc[1] = __builtin_amdgcn_mfma_f32_16x16x32_bf16(ap1, vones, lacc[1], 0, 0, 0);
            for (int nj = 0; nj < 8; nj++) {
                bf16x8 bv = *(const bf16x8*)(Vs + (nj * 16 + l16) * VSP + ks2 * 32 + quad * 8);
                oacc[0][nj] = __builtin_amdgcn_mfma_f32_16x16x32_bf16(ap0, bv, oacc[0][nj], 0, 0, 0);
                oacc[1][nj] = __builtin_amdgcn_mfma_f32_16x16x32_bf16(ap1, bv, oacc[1][nj], 0, 0, 0);
            }
        }
    }

    if (!split) {
        short* Obase = Ocat + (size_t)(b * TT) * HIDDEN + h * HDIM;
        for (int g = 0; g < 2; g++) {
            float inv[4];
            for (int r = 0; r < 4; r++) inv[r] = 1.0f / lacc[g][r];
            for (int nj = 0; nj < 8; nj++)
                for (int r = 0; r < 4; r++)
                    Obase[(size_t)irow[g][r] * HIDDEN + nj * 16 + l16] = f2bf(oacc[g][nj][r] * inv[r]);
        }
    } else {
        // deterministic partial slot per (ck, bh); rows 1536..2047 -> [0,512)
        float* Ob = Opart + ((size_t)(ck * 28 + bh) * 512) * 128;
        float* lb = lpart + (ck * 28 + bh) * 512;
        for (int g = 0; g < 2; g++) {
            for (int nj = 0; nj < 8; nj++)
                for (int r = 0; r < 4; r++)
                    Ob[(size_t)(irow[g][r] - 1536) * 128 + nj * 16 + l16] = oacc[g][nj][r];
            if (l16 == 0)
                for (int r = 0; r < 4; r++)
                    lb[irow[g][r] - 1536] = lacc[g][r];
        }
    }
}

// ---------------- kernel 3.5: merge the two causal split chunks ----------------
__global__ __launch_bounds__(256) void attn_merge(const float* __restrict__ Opart,
                                                  const float* __restrict__ lpart,
                                                  short* __restrict__ Ocat,
                                                  const int* __restrict__ iscp) {
    if (!*iscp) return;
    const int CKS = 28 * 512 * 128;     // floats per chunk set
    int idx = blockIdx.x * 256 + threadIdx.x;   // 458,752 float4s total
    int e = idx * 4;
    if (e >= CKS) return;
    int bh = e >> 16;                   // / (512*128)
    int rem = e & 65535;
    int row = rem >> 7, col = rem & 127;
    int h = bh >> 2, bb = bh & 3;
    float inv = 1.0f / (lpart[bh * 512 + row] + lpart[28 * 512 + bh * 512 + row]);
    float4 fa = *(const float4*)(Opart + e);
    float4 fb = *(const float4*)(Opart + CKS + e);
    short4 o;
    o.x = f2bf((fa.x + fb.x) * inv); o.y = f2bf((fa.y + fb.y) * inv);
    o.z = f2bf((fa.z + fb.z) * inv); o.w = f2bf((fa.w + fb.w) * inv);
    *(short4*)(Ocat + (size_t)(bb * TT + 1536 + row) * HIDDEN + h * HDIM + col) = o;
}

// ---------------- kernel 4: output projection (128x128, global_load_lds) ----------------
// grid (7 n, 64 m): x=n fastest -> consecutive blocks share the A tile (L2-hot),
// all 7 B panels (1.6 MB) stay resident.
__global__ __launch_bounds__(256) void out_gemm(
    const short* __restrict__ A, const short* __restrict__ Bt, float* __restrict__ out)
{
    __shared__ short Ash[128 * 32];
    __shared__ short Bsh[128 * 32];
    const int n0 = blockIdx.x * 128;
    const int m0 = blockIdx.y * 128;

    const int tid = threadIdx.x;
    const int wave = tid >> 6, lane = tid & 63;
    const int quad = lane >> 4, l16 = lane & 15;
    const int wm = (wave >> 1) * 64, wn = (wave & 1) * 64;

    f32x4 acc[4][4] = {};

    const int r0 = tid >> 2, cc0 = (tid & 3) * 8;
    const int r1 = r0 + 64;
    short* adst0 = Ash + wave * 512;
    short* adst1 = Ash + 2048 + wave * 512;
    short* bdst0 = Bsh + wave * 512;
    short* bdst1 = Bsh + 2048 + wave * 512;
    const short* asrc0 = A + (size_t)(m0 + r0) * HIDDEN + cc0;
    const short* asrc1 = A + (size_t)(m0 + r1) * HIDDEN + cc0;
    const short* bsrc0 = Bt + (size_t)(n0 + r0) * HIDDEN + cc0;
    const short* bsrc1 = Bt + (size_t)(n0 + r1) * HIDDEN + cc0;

    for (int k0 = 0; k0 < HIDDEN; k0 += 32) {
        __syncthreads();
        gll16(asrc0 + k0, adst0);
        gll16(asrc1 + k0, adst1);
        gll16(bsrc0 + k0, bdst0);
        gll16(bsrc1 + k0, bdst1);
        __syncthreads();
        bf16x8 af[4], bfr[4];
        for (int mi = 0; mi < 4; mi++)
            af[mi] = *(const bf16x8*)(Ash + (wm + mi * 16 + l16) * 32 + quad * 8);
        for (int ni = 0; ni < 4; ni++)
            bfr[ni] = *(const bf16x8*)(Bsh + (wn + ni * 16 + l16) * 32 + quad * 8);
        for (int mi = 0; mi < 4; mi++)
            for (int ni = 0; ni < 4; ni++)
                acc[mi][ni] = __builtin_amdgcn_mfma_f32_16x16x32_bf16(af[mi], bfr[ni], acc[mi][ni], 0, 0, 0);
    }

    for (int mi = 0; mi < 4; mi++)
        for (int ni = 0; ni < 4; ni++)
            for (int r = 0; r < 4; r++) {
                int m = m0 + wm + mi * 16 + quad * 4 + r;
                int n = n0 + wn + ni * 16 + l16;
                out[(size_t)m * HIDDEN + n] = acc[mi][ni][r];
            }
}

extern "C" void kernel_launch(void* const* d_in, const int* in_sizes, int n_in,
                              void* d_out, int out_size, void* d_ws, size_t ws_size,
                              hipStream_t stream) {
    (void)in_sizes; (void)n_in; (void)out_size; (void)ws_size;
    const float* x  = (const float*)d_in[0];
    const float* Wq = (const float*)d_in[1];
    const float* Wk = (const float*)d_in[2];
    const float* Wv = (const float*)d_in[3];
    const float* Wo = (const float*)d_in[4];
    const int* iscp = (const int*)d_in[5];
    float* out = (float*)d_out;

    short* xb   = (short*)d_ws;                       // 8192*896 shorts = 14,680,064 B
    short* Qb   = xb   + (size_t)MTOT * HIDDEN;       // 7*8192*128 each
    short* Kb   = Qb   + (size_t)HEADS * MTOT * HDIM;
    short* Vtb  = Kb   + (size_t)HEADS * MTOT * HDIM;
    short* Ocat = Vtb  + (size_t)HEADS * MTOT * HDIM; // 8192*896 (aliased with Wt)
    short* Wt   = Ocat;                               // 21*128*896, used only before attn
    short* Wob  = Ocat + (size_t)MTOT * HIDDEN;       // 896*896
    // split-S partials: 2 chunks * 28 bh * 512 rows * 128 f32 = 14,680,064 B == xb exactly
    float* Opart = (float*)d_ws;                      // aliases xb (dead after qkv_gemm)
    float* lpart = (float*)(Wob + (size_t)HIDDEN * HIDDEN);  // 2*28*512 f32 = 114,688 B

    cast_x_kernel<<<(MTOT * HIDDEN) / (256 * 4), 256, 0, stream>>>(x, xb);
    cast_wo_kernel<<<(HIDDEN * HIDDEN) / (256 * 4), 256, 0, stream>>>(Wo, Wob);
    transpose_cast_w<<<dim3(HIDDEN / 32, HDIM / 32, 21), 256, 0, stream>>>(Wq, Wk, Wv, Wt);
    qkv_gemm<<<dim3(21, MTOT / 128), 256, 0, stream>>>(xb, Wt, Qb, Kb, Vtb);
    fano_attn<<<dim3(BB * HEADS, TT / 128, 2), 256, 0, stream>>>(Qb, Kb, Vtb, Ocat, Opart, lpart, iscp);
    attn_merge<<<(28 * 512 * 128 / 4) / 256, 256, 0, stream>>>(Opart, lpart, Ocat, iscp);
    out_gemm<<<dim3(HIDDEN / 128, MTOT / 128), 256, 0, stream>>>(Ocat, Wob, out);
}